// Round 1
// baseline (1049.118 us; speedup 1.0000x reference)
//
#include <hip/hip_runtime.h>

#define NN 50000
#define EE 640000
#define RR 8

typedef __bf16 bf16x8 __attribute__((ext_vector_type(8)));
typedef float  f32x4  __attribute__((ext_vector_type(4)));

__device__ __forceinline__ unsigned short f2b(float f) {
  unsigned int u = __float_as_uint(f);
  u += 0x7fffu + ((u >> 16) & 1u);          // round-to-nearest-even
  return (unsigned short)(u >> 16);
}
__device__ __forceinline__ float b2f(unsigned short h) {
  return __uint_as_float(((unsigned int)h) << 16);
}

// ---- f32 -> bf16 bulk convert (x4 vectorized) ----
__global__ void k_f32_to_bf16_x4(const float* __restrict__ src,
                                 unsigned short* __restrict__ dst, int n4) {
  int t = blockIdx.x * blockDim.x + threadIdx.x;
  if (t >= n4) return;
  float4 v = reinterpret_cast<const float4*>(src)[t];
  ushort4 o = make_ushort4(f2b(v.x), f2b(v.y), f2b(v.z), f2b(v.w));
  reinterpret_cast<ushort4*>(dst)[t] = o;
}

// ---- build B^T for layer 1: [1152][128], rows j = r*128+o (r<8) then root ----
__global__ void k_build_b1(const float* __restrict__ W1, const float* __restrict__ root1,
                           unsigned short* __restrict__ B1T) {
  int t = blockIdx.x * 256 + threadIdx.x;
  if (t >= 1152 * 128) return;
  int j = t >> 7, k = t & 127;
  float v = (j < 1024) ? W1[((j >> 7) << 14) + (k << 7) + (j & 127)]
                       : root1[(k << 7) + (j - 1024)];
  B1T[t] = f2b(v);
}

// ---- build B^T for layer 2: [640][128], rows j = r*64+o (r<8), root, zero-pad ----
__global__ void k_build_b2(const float* __restrict__ W2, const float* __restrict__ root2,
                           unsigned short* __restrict__ B2T) {
  int t = blockIdx.x * 256 + threadIdx.x;
  if (t >= 640 * 128) return;
  int j = t >> 7, k = t & 127;
  float v = 0.0f;
  if (j < 512)      v = W2[((j >> 6) << 13) + (k << 6) + (j & 63)];
  else if (j < 576) v = root2[(k << 6) + (j - 512)];
  B2T[t] = f2b(v);
}

// ---- per-(relation,dst) degree count ----
__global__ void k_count(const int* __restrict__ dst, const int* __restrict__ typ,
                        int* __restrict__ cnt) {
  int e = blockIdx.x * 256 + threadIdx.x;
  if (e >= EE) return;
  atomicAdd(&cnt[typ[e] * NN + dst[e]], 1);
}

__global__ void k_rinv(const int* __restrict__ cnt, float* __restrict__ rinv) {
  int i = blockIdx.x * 256 + threadIdx.x;
  if (i >= RR * NN) return;
  int c = cnt[i];
  rinv[i] = (c > 0) ? 1.0f / (float)c : 1.0f;
}

// ---- bf16 MFMA GEMM: A[M,128] @ B[128, gridDim.y*128] (B given transposed [n][k]).
// cols < nsplit  -> Y (bf16, stride nsplit)
// cols [nsplit, nsplit+nroot) -> rootOut (f32, stride nroot) + bias
// cols beyond    -> dropped (zero pad)
__global__ __launch_bounds__(256, 2) void k_gemm(
    const unsigned short* __restrict__ A, const unsigned short* __restrict__ BT,
    unsigned short* __restrict__ Y, float* __restrict__ rootOut,
    const float* __restrict__ bias, int M, int nsplit, int nroot) {
  __shared__ __align__(16) unsigned short As[128][128];
  __shared__ __align__(16) unsigned short Bs[128][128];
  const int tid = threadIdx.x;
  const int m0 = blockIdx.x * 128;
  const int n0 = blockIdx.y * 128;
#pragma unroll
  for (int i = 0; i < 8; ++i) {
    int c = tid + i * 256;            // 2048 16B-chunks per tile
    int row = c >> 4;
    int col8 = (c & 15) << 3;
    uint4 av = make_uint4(0u, 0u, 0u, 0u);
    if (m0 + row < M)
      av = *reinterpret_cast<const uint4*>(&A[(size_t)(m0 + row) * 128 + col8]);
    *reinterpret_cast<uint4*>(&As[row][col8]) = av;
    uint4 bv = *reinterpret_cast<const uint4*>(&BT[(size_t)(n0 + row) * 128 + col8]);
    *reinterpret_cast<uint4*>(&Bs[row][col8]) = bv;
  }
  __syncthreads();
  const int lane = tid & 63;
  const int wave = tid >> 6;
  const int wm = (wave >> 1) << 6;
  const int wn = (wave & 1) << 6;
  const int l15 = lane & 15;
  const int quad = lane >> 4;
  f32x4 acc[4][4] = {};
#pragma unroll
  for (int kk = 0; kk < 4; ++kk) {
    const int kb = kk * 32 + quad * 8;
    bf16x8 af[4], bfr[4];
#pragma unroll
    for (int i = 0; i < 4; ++i) {
      af[i]  = *reinterpret_cast<const bf16x8*>(&As[wm + i * 16 + l15][kb]);
      bfr[i] = *reinterpret_cast<const bf16x8*>(&Bs[wn + i * 16 + l15][kb]);
    }
#pragma unroll
    for (int i = 0; i < 4; ++i)
#pragma unroll
      for (int j = 0; j < 4; ++j)
        acc[i][j] = __builtin_amdgcn_mfma_f32_16x16x32_bf16(af[i], bfr[j], acc[i][j], 0, 0, 0);
  }
#pragma unroll
  for (int i = 0; i < 4; ++i) {
#pragma unroll
    for (int r = 0; r < 4; ++r) {
      const int grow = m0 + wm + i * 16 + quad * 4 + r;
      if (grow >= M) continue;
#pragma unroll
      for (int j = 0; j < 4; ++j) {
        const int gcol = n0 + wn + j * 16 + l15;
        const float v = acc[i][j][r];
        if (gcol < nsplit) {
          Y[(size_t)grow * nsplit + gcol] = f2b(v);
        } else if (gcol < nsplit + nroot) {
          rootOut[(size_t)grow * nroot + (gcol - nsplit)] = v + bias[gcol - nsplit];
        }
      }
    }
  }
}

// ---- layer-1 scatter: one wave per edge, 2 feats/thread, 128 feats ----
__global__ void k_scatter1(const int* __restrict__ src, const int* __restrict__ dst,
                           const int* __restrict__ typ, const unsigned short* __restrict__ y,
                           const float* __restrict__ rinv, float* __restrict__ acc) {
  int t = blockIdx.x * 256 + threadIdx.x;
  int e = t >> 6;
  if (e >= EE) return;
  int f2 = (t & 63) << 1;
  int s = src[e], d = dst[e], r = typ[e];
  float sc = rinv[r * NN + d];
  unsigned int pk = *reinterpret_cast<const unsigned int*>(&y[(size_t)s * 1024 + (r << 7) + f2]);
  float v0 = b2f((unsigned short)(pk & 0xffffu)) * sc;
  float v1 = __uint_as_float(pk & 0xffff0000u) * sc;
  unsafeAtomicAdd(&acc[(size_t)d * 128 + f2], v0);
  unsafeAtomicAdd(&acc[(size_t)d * 128 + f2 + 1], v1);
}

// ---- layer-2 scatter: half-wave per edge, 64 feats ----
__global__ void k_scatter2(const int* __restrict__ src, const int* __restrict__ dst,
                           const int* __restrict__ typ, const unsigned short* __restrict__ y,
                           const float* __restrict__ rinv, float* __restrict__ acc) {
  int t = blockIdx.x * 256 + threadIdx.x;
  int e = t >> 5;
  if (e >= EE) return;
  int f2 = (t & 31) << 1;
  int s = src[e], d = dst[e], r = typ[e];
  float sc = rinv[r * NN + d];
  unsigned int pk = *reinterpret_cast<const unsigned int*>(&y[(size_t)s * 512 + (r << 6) + f2]);
  float v0 = b2f((unsigned short)(pk & 0xffffu)) * sc;
  float v1 = __uint_as_float(pk & 0xffff0000u) * sc;
  unsafeAtomicAdd(&acc[(size_t)d * 64 + f2], v0);
  unsafeAtomicAdd(&acc[(size_t)d * 64 + f2 + 1], v1);
}

// ---- relu + f32->bf16 (x4) ----
__global__ void k_relu_to_bf16_x4(const float* __restrict__ in,
                                  unsigned short* __restrict__ out, int n4) {
  int t = blockIdx.x * blockDim.x + threadIdx.x;
  if (t >= n4) return;
  float4 v = reinterpret_cast<const float4*>(in)[t];
  ushort4 o = make_ushort4(f2b(fmaxf(v.x, 0.f)), f2b(fmaxf(v.y, 0.f)),
                           f2b(fmaxf(v.z, 0.f)), f2b(fmaxf(v.w, 0.f)));
  reinterpret_cast<ushort4*>(out)[t] = o;
}

// ---- classifier: relu(out2) @ Wc + bc, one wave per node ----
__global__ void k_cls(const float* __restrict__ h, const float* __restrict__ Wc,
                      const float* __restrict__ bc, float* __restrict__ out) {
  int node = blockIdx.x * 4 + (threadIdx.x >> 6);
  int lane = threadIdx.x & 63;
  float v = (node < NN) ? fmaxf(h[(size_t)node * 64 + lane], 0.f) : 0.f;
  float p0 = v * Wc[lane * 2 + 0];
  float p1 = v * Wc[lane * 2 + 1];
#pragma unroll
  for (int off = 32; off > 0; off >>= 1) {
    p0 += __shfl_down(p0, off, 64);
    p1 += __shfl_down(p1, off, 64);
  }
  if (lane == 0 && node < NN) {
    out[node * 2 + 0] = p0 + bc[0];
    out[node * 2 + 1] = p1 + bc[1];
  }
}

extern "C" void kernel_launch(void* const* d_in, const int* in_sizes, int n_in,
                              void* d_out, int out_size, void* d_ws, size_t ws_size,
                              hipStream_t stream) {
  const float* x     = (const float*)d_in[0];
  const int*   ei    = (const int*)d_in[1];
  const int*   et    = (const int*)d_in[2];
  const float* W1    = (const float*)d_in[3];
  const float* root1 = (const float*)d_in[4];
  const float* b1    = (const float*)d_in[5];
  const float* W2    = (const float*)d_in[6];
  const float* root2 = (const float*)d_in[7];
  const float* b2    = (const float*)d_in[8];
  const float* Wc    = (const float*)d_in[9];
  const float* bc    = (const float*)d_in[10];
  const int* srcI = ei;        // edge_index[0]
  const int* dstI = ei + EE;   // edge_index[1]

  char* ws = (char*)d_ws;
  unsigned short* xb   = (unsigned short*)(ws);                 // 12,800,000 B
  float*          out2 = (float*)(ws);                          // alias (xb dead after gemm1)
  unsigned short* B1T  = (unsigned short*)(ws + 12800000);      //    294,912 B
  unsigned short* B2T  = (unsigned short*)(ws + 13094912);      //    163,840 B
  int*            cnt  = (int*)(ws + 13258752);                 //  1,600,000 B
  float*          rinv = (float*)(ws + 14858752);               //  1,600,000 B
  float*          hpre = (float*)(ws + 16458752);               // 25,600,000 B
  unsigned short* hbf  = (unsigned short*)(ws + 42058752);      // 12,800,000 B
  unsigned short* y1   = (unsigned short*)(ws + 54858752);      // 102,400,000 B
  unsigned short* y2   = y1;                                    // alias (y1 dead after scatter1)
  // total: 157,258,752 B

  hipMemsetAsync(cnt, 0, RR * NN * sizeof(int), stream);
  k_f32_to_bf16_x4<<<(1600000 + 255) / 256, 256, 0, stream>>>(x, xb, 1600000);
  k_build_b1<<<(1152 * 128 + 255) / 256, 256, 0, stream>>>(W1, root1, B1T);
  k_build_b2<<<(640 * 128 + 255) / 256, 256, 0, stream>>>(W2, root2, B2T);
  k_count<<<(EE + 255) / 256, 256, 0, stream>>>(dstI, et, cnt);
  k_rinv<<<(RR * NN + 255) / 256, 256, 0, stream>>>(cnt, rinv);

  // layer 1: y1 = xb @ [W1_0..W1_7] (bf16), hpre = xb @ root1 + b1 (f32)
  k_gemm<<<dim3(391, 9), 256, 0, stream>>>(xb, B1T, y1, hpre, b1, NN, 1024, 128);
  k_scatter1<<<160000, 256, 0, stream>>>(srcI, dstI, et, y1, rinv, hpre);
  k_relu_to_bf16_x4<<<(1600000 + 255) / 256, 256, 0, stream>>>(hpre, hbf, 1600000);

  // layer 2: y2 = hbf @ [W2_0..W2_7] (bf16), out2 = hbf @ root2 + b2 (f32)
  k_gemm<<<dim3(391, 5), 256, 0, stream>>>(hbf, B2T, y2, out2, b2, NN, 512, 64);
  k_scatter2<<<80000, 256, 0, stream>>>(srcI, dstI, et, y2, rinv, out2);

  k_cls<<<(NN + 3) / 4, 256, 0, stream>>>(out2, Wc, bc, (float*)d_out);
}

// Round 2
// 404.300 us; speedup vs baseline: 2.5949x; 2.5949x over previous
//
#include <hip/hip_runtime.h>

#define NN 50000
#define EE 640000
#define RR 8
#define CAP 64   // per-dst edge capacity; deg ~ Binom(640K, 1/50K), P(deg>=64) ~ 1e-26

typedef __bf16 bf16x8 __attribute__((ext_vector_type(8)));
typedef float  f32x4  __attribute__((ext_vector_type(4)));

__device__ __forceinline__ unsigned short f2b(float f) {
  unsigned int u = __float_as_uint(f);
  u += 0x7fffu + ((u >> 16) & 1u);          // round-to-nearest-even
  return (unsigned short)(u >> 16);
}
__device__ __forceinline__ float b2f(unsigned short h) {
  return __uint_as_float(((unsigned int)h) << 16);
}

// ---- f32 -> bf16 bulk convert (x4 vectorized) ----
__global__ void k_f32_to_bf16_x4(const float* __restrict__ src,
                                 unsigned short* __restrict__ dst, int n4) {
  int t = blockIdx.x * blockDim.x + threadIdx.x;
  if (t >= n4) return;
  float4 v = reinterpret_cast<const float4*>(src)[t];
  ushort4 o = make_ushort4(f2b(v.x), f2b(v.y), f2b(v.z), f2b(v.w));
  reinterpret_cast<ushort4*>(dst)[t] = o;
}

// ---- build B^T for layer 1: [1152][128], rows j = r*128+o (r<8) then root ----
__global__ void k_build_b1(const float* __restrict__ W1, const float* __restrict__ root1,
                           unsigned short* __restrict__ B1T) {
  int t = blockIdx.x * 256 + threadIdx.x;
  if (t >= 1152 * 128) return;
  int j = t >> 7, k = t & 127;
  float v = (j < 1024) ? W1[((j >> 7) << 14) + (k << 7) + (j & 127)]
                       : root1[(k << 7) + (j - 1024)];
  B1T[t] = f2b(v);
}

// ---- build B^T for layer 2: [640][128], rows j = r*64+o (r<8), root, zero-pad ----
__global__ void k_build_b2(const float* __restrict__ W2, const float* __restrict__ root2,
                           unsigned short* __restrict__ B2T) {
  int t = blockIdx.x * 256 + threadIdx.x;
  if (t >= 640 * 128) return;
  int j = t >> 7, k = t & 127;
  float v = 0.0f;
  if (j < 512)      v = W2[((j >> 6) << 13) + (k << 6) + (j & 63)];
  else if (j < 576) v = root2[(k << 6) + (j - 512)];
  B2T[t] = f2b(v);
}

// ---- one edge pass: per-(r,dst) count + per-dst CSR-with-capacity build ----
__global__ void k_edges(const int* __restrict__ src, const int* __restrict__ dst,
                        const int* __restrict__ typ, int* __restrict__ cnt,
                        int* __restrict__ cursor, unsigned int* __restrict__ entries) {
  int e = blockIdx.x * 256 + threadIdx.x;
  if (e >= EE) return;
  int d = dst[e], r = typ[e];
  atomicAdd(&cnt[r * NN + d], 1);
  int pos = atomicAdd(&cursor[d], 1);
  if (pos < CAP)
    entries[d * CAP + pos] = (unsigned int)src[e] | ((unsigned int)r << 16);
}

// ---- rinv in place over cnt (int -> float, elementwise) ----
__global__ void k_rinv(int* __restrict__ cnt) {
  int i = blockIdx.x * 256 + threadIdx.x;
  if (i >= RR * NN) return;
  int c = cnt[i];
  reinterpret_cast<float*>(cnt)[i] = (c > 0) ? 1.0f / (float)c : 1.0f;
}

// ---- bf16 MFMA GEMM: A[M,128] @ B[128, gridDim.y*128] (B given transposed [n][k]).
// cols < nsplit  -> Y (bf16, stride nsplit)
// cols [nsplit, nsplit+nroot) -> rootOut (f32, stride nroot) + bias
// cols beyond    -> dropped (zero pad)
__global__ __launch_bounds__(256, 2) void k_gemm(
    const unsigned short* __restrict__ A, const unsigned short* __restrict__ BT,
    unsigned short* __restrict__ Y, float* __restrict__ rootOut,
    const float* __restrict__ bias, int M, int nsplit, int nroot) {
  __shared__ __align__(16) unsigned short As[128][128];
  __shared__ __align__(16) unsigned short Bs[128][128];
  const int tid = threadIdx.x;
  const int m0 = blockIdx.x * 128;
  const int n0 = blockIdx.y * 128;
#pragma unroll
  for (int i = 0; i < 8; ++i) {
    int c = tid + i * 256;            // 2048 16B-chunks per tile
    int row = c >> 4;
    int col8 = (c & 15) << 3;
    uint4 av = make_uint4(0u, 0u, 0u, 0u);
    if (m0 + row < M)
      av = *reinterpret_cast<const uint4*>(&A[(size_t)(m0 + row) * 128 + col8]);
    *reinterpret_cast<uint4*>(&As[row][col8]) = av;
    uint4 bv = *reinterpret_cast<const uint4*>(&BT[(size_t)(n0 + row) * 128 + col8]);
    *reinterpret_cast<uint4*>(&Bs[row][col8]) = bv;
  }
  __syncthreads();
  const int lane = tid & 63;
  const int wave = tid >> 6;
  const int wm = (wave >> 1) << 6;
  const int wn = (wave & 1) << 6;
  const int l15 = lane & 15;
  const int quad = lane >> 4;
  f32x4 acc[4][4] = {};
#pragma unroll
  for (int kk = 0; kk < 4; ++kk) {
    const int kb = kk * 32 + quad * 8;
    bf16x8 af[4], bfr[4];
#pragma unroll
    for (int i = 0; i < 4; ++i) {
      af[i]  = *reinterpret_cast<const bf16x8*>(&As[wm + i * 16 + l15][kb]);
      bfr[i] = *reinterpret_cast<const bf16x8*>(&Bs[wn + i * 16 + l15][kb]);
    }
#pragma unroll
    for (int i = 0; i < 4; ++i)
#pragma unroll
      for (int j = 0; j < 4; ++j)
        acc[i][j] = __builtin_amdgcn_mfma_f32_16x16x32_bf16(af[i], bfr[j], acc[i][j], 0, 0, 0);
  }
#pragma unroll
  for (int i = 0; i < 4; ++i) {
#pragma unroll
    for (int r = 0; r < 4; ++r) {
      const int grow = m0 + wm + i * 16 + quad * 4 + r;
      if (grow >= M) continue;
#pragma unroll
      for (int j = 0; j < 4; ++j) {
        const int gcol = n0 + wn + j * 16 + l15;
        const float v = acc[i][j][r];
        if (gcol < nsplit) {
          Y[(size_t)grow * nsplit + gcol] = f2b(v);
        } else if (gcol < nsplit + nroot) {
          rootOut[(size_t)grow * nroot + (gcol - nsplit)] = v + bias[gcol - nsplit];
        }
      }
    }
  }
}

// ---- layer-1 pull-aggregate: one wave per dst, 2 feats/lane (128 feats).
// out = relu(hpre + sum_e y1[src_e, r_e*128 + f] * rinv[r_e,d])  -> packed bf16
__global__ void k_agg1(const unsigned int* __restrict__ entries,
                       const int* __restrict__ cursor,
                       const unsigned short* __restrict__ y,
                       const float* __restrict__ rinv,
                       const float* __restrict__ hpre,
                       unsigned int* __restrict__ hbf) {
  int d = blockIdx.x * 4 + (threadIdx.x >> 6);
  if (d >= NN) return;
  int lane = threadIdx.x & 63;
  int deg = cursor[d];
  if (deg > CAP) deg = CAP;
  float a0 = 0.f, a1 = 0.f;
  const unsigned int* ep = &entries[d * CAP];
  for (int i = 0; i < deg; ++i) {
    unsigned int e = ep[i];
    int s = e & 0xffffu;
    int r = e >> 16;
    float sc = rinv[r * NN + d];
    unsigned int pk = *reinterpret_cast<const unsigned int*>(
        &y[(size_t)s * 1024 + (r << 7) + (lane << 1)]);
    a0 += b2f((unsigned short)(pk & 0xffffu)) * sc;
    a1 += __uint_as_float(pk & 0xffff0000u) * sc;
  }
  float2 h = reinterpret_cast<const float2*>(hpre)[(size_t)d * 64 + lane];
  a0 = fmaxf(a0 + h.x, 0.f);
  a1 = fmaxf(a1 + h.y, 0.f);
  hbf[(size_t)d * 64 + lane] = (unsigned int)f2b(a0) | ((unsigned int)f2b(a1) << 16);
}

// ---- layer-2 pull-aggregate + classifier: one wave per dst, 64 feats.
// lanes 0-31 / 32-63 each take alternate edges (2 feats/lane), combine via xor-shuffle,
// then relu + (64x2) matvec with wave reduction -> logits.
__global__ void k_agg2(const unsigned int* __restrict__ entries,
                       const int* __restrict__ cursor,
                       const unsigned short* __restrict__ y,
                       const float* __restrict__ rinv,
                       const float* __restrict__ hpre,
                       const float* __restrict__ Wc, const float* __restrict__ bc,
                       float* __restrict__ out) {
  int d = blockIdx.x * 4 + (threadIdx.x >> 6);
  if (d >= NN) return;
  int lane = threadIdx.x & 63;
  int half = lane >> 5;
  int l32 = lane & 31;
  int deg = cursor[d];
  if (deg > CAP) deg = CAP;
  float a0 = 0.f, a1 = 0.f;
  const unsigned int* ep = &entries[d * CAP];
  for (int i = half; i < deg; i += 2) {
    unsigned int e = ep[i];
    int s = e & 0xffffu;
    int r = e >> 16;
    float sc = rinv[r * NN + d];
    unsigned int pk = *reinterpret_cast<const unsigned int*>(
        &y[(size_t)s * 512 + (r << 6) + (l32 << 1)]);
    a0 += b2f((unsigned short)(pk & 0xffffu)) * sc;
    a1 += __uint_as_float(pk & 0xffff0000u) * sc;
  }
  a0 += __shfl_xor(a0, 32, 64);
  a1 += __shfl_xor(a1, 32, 64);
  float2 h = reinterpret_cast<const float2*>(hpre)[(size_t)d * 32 + l32];
  float v0 = fmaxf(a0 + h.x, 0.f);
  float v1 = fmaxf(a1 + h.y, 0.f);
  int f0 = l32 << 1;
  float p0 = v0 * Wc[f0 * 2 + 0] + v1 * Wc[f0 * 2 + 2];
  float p1 = v0 * Wc[f0 * 2 + 1] + v1 * Wc[f0 * 2 + 3];
#pragma unroll
  for (int off = 16; off > 0; off >>= 1) {
    p0 += __shfl_down(p0, off, 64);
    p1 += __shfl_down(p1, off, 64);
  }
  if (lane == 0) {
    out[d * 2 + 0] = p0 + bc[0];
    out[d * 2 + 1] = p1 + bc[1];
  }
}

extern "C" void kernel_launch(void* const* d_in, const int* in_sizes, int n_in,
                              void* d_out, int out_size, void* d_ws, size_t ws_size,
                              hipStream_t stream) {
  const float* x     = (const float*)d_in[0];
  const int*   ei    = (const int*)d_in[1];
  const int*   et    = (const int*)d_in[2];
  const float* W1    = (const float*)d_in[3];
  const float* root1 = (const float*)d_in[4];
  const float* b1    = (const float*)d_in[5];
  const float* W2    = (const float*)d_in[6];
  const float* root2 = (const float*)d_in[7];
  const float* b2    = (const float*)d_in[8];
  const float* Wc    = (const float*)d_in[9];
  const float* bc    = (const float*)d_in[10];
  const int* srcI = ei;        // edge_index[0]
  const int* dstI = ei + EE;   // edge_index[1]

  char* ws = (char*)d_ws;
  unsigned short* xb      = (unsigned short*)(ws);             // 12,800,000 B
  unsigned int*   hbf     = (unsigned int*)(ws);               // alias (xb dead after gemm1)
  unsigned short* B1T     = (unsigned short*)(ws + 12800000);  //    294,912 B
  unsigned short* B2T     = (unsigned short*)(ws + 13094912);  //    163,840 B
  int*            cnt     = (int*)(ws + 13258752);             //  1,600,000 B (becomes rinv in place)
  float*          rinv    = (float*)(ws + 13258752);           //  alias of cnt
  int*            cursor  = (int*)(ws + 14858752);             //    200,000 B
  unsigned int*   entries = (unsigned int*)(ws + 15058752);    // 12,800,000 B (50000*64*4)
  float*          hpre    = (float*)(ws + 27858752);           // 25,600,000 B (reused layer 2)
  unsigned short* y1      = (unsigned short*)(ws + 53458752);  // 102,400,000 B
  unsigned short* y2      = y1;                                // alias (y1 dead after agg1)
  // total: 155,858,752 B

  hipMemsetAsync(cnt, 0, 1800000, stream);  // cnt + cursor contiguous
  k_f32_to_bf16_x4<<<(1600000 + 255) / 256, 256, 0, stream>>>(x, xb, 1600000);
  k_build_b1<<<(1152 * 128 + 255) / 256, 256, 0, stream>>>(W1, root1, B1T);
  k_build_b2<<<(640 * 128 + 255) / 256, 256, 0, stream>>>(W2, root2, B2T);
  k_edges<<<(EE + 255) / 256, 256, 0, stream>>>(srcI, dstI, et, cnt, cursor, entries);
  k_rinv<<<(RR * NN + 255) / 256, 256, 0, stream>>>(cnt);

  // layer 1: y1 = xb @ [W1_0..W1_7] (bf16), hpre = xb @ root1 + b1 (f32)
  k_gemm<<<dim3(391, 9), 256, 0, stream>>>(xb, B1T, y1, hpre, b1, NN, 1024, 128);
  k_agg1<<<(NN + 3) / 4, 256, 0, stream>>>(entries, cursor, y1, rinv, hpre, hbf);

  // layer 2: y2 = hbf @ [W2_0..W2_7] (bf16), hpre = hbf @ root2 + b2 (f32)
  k_gemm<<<dim3(391, 5), 256, 0, stream>>>((const unsigned short*)hbf, B2T, y2, hpre, b2, NN, 512, 64);
  k_agg2<<<(NN + 3) / 4, 256, 0, stream>>>(entries, cursor, y2, rinv, hpre, Wc, bc, (float*)d_out);
}

// Round 3
// 281.531 us; speedup vs baseline: 3.7265x; 1.4361x over previous
//
#include <hip/hip_runtime.h>

#define NN 50000
#define EE 640000
#define RR 8
#define CAP 64   // per-dst edge capacity; deg ~ Binom(640K, 1/50K), P(deg>=64) ~ 1e-26

typedef __bf16 bf16x8 __attribute__((ext_vector_type(8)));
typedef float  f32x4  __attribute__((ext_vector_type(4)));
typedef const __attribute__((address_space(1))) unsigned int* gas_p;
typedef __attribute__((address_space(3))) unsigned int* las_p;

__device__ __forceinline__ unsigned short f2b(float f) {
  unsigned int u = __float_as_uint(f);
  u += 0x7fffu + ((u >> 16) & 1u);          // round-to-nearest-even
  return (unsigned short)(u >> 16);
}
__device__ __forceinline__ float b2f(unsigned short h) {
  return __uint_as_float(((unsigned int)h) << 16);
}

// ---- f32 -> bf16 bulk convert (x4 vectorized) ----
__global__ void k_f32_to_bf16_x4(const float* __restrict__ src,
                                 unsigned short* __restrict__ dst, int n4) {
  int t = blockIdx.x * blockDim.x + threadIdx.x;
  if (t >= n4) return;
  float4 v = reinterpret_cast<const float4*>(src)[t];
  ushort4 o = make_ushort4(f2b(v.x), f2b(v.y), f2b(v.z), f2b(v.w));
  reinterpret_cast<ushort4*>(dst)[t] = o;
}

// ---- build B^T for layer 1: [1152][128], rows j = r*128+o (r<8) then root ----
__global__ void k_build_b1(const float* __restrict__ W1, const float* __restrict__ root1,
                           unsigned short* __restrict__ B1T) {
  int t = blockIdx.x * 256 + threadIdx.x;
  if (t >= 1152 * 128) return;
  int j = t >> 7, k = t & 127;
  float v = (j < 1024) ? W1[((j >> 7) << 14) + (k << 7) + (j & 127)]
                       : root1[(k << 7) + (j - 1024)];
  B1T[t] = f2b(v);
}

// ---- build B^T for layer 2: [640][128], rows j = r*64+o (r<8), root, zero-pad ----
__global__ void k_build_b2(const float* __restrict__ W2, const float* __restrict__ root2,
                           unsigned short* __restrict__ B2T) {
  int t = blockIdx.x * 256 + threadIdx.x;
  if (t >= 640 * 128) return;
  int j = t >> 7, k = t & 127;
  float v = 0.0f;
  if (j < 512)      v = W2[((j >> 6) << 13) + (k << 6) + (j & 63)];
  else if (j < 576) v = root2[(k << 6) + (j - 512)];
  B2T[t] = f2b(v);
}

// ---- edge pass: per-dst edge-list build (src|r packed); counts come from ballots ----
__global__ void k_edges(const int* __restrict__ src, const int* __restrict__ dst,
                        const int* __restrict__ typ,
                        int* __restrict__ cursor, unsigned int* __restrict__ entries) {
  int e = blockIdx.x * 256 + threadIdx.x;
  if (e >= EE) return;
  int d = dst[e], r = typ[e];
  int pos = atomicAdd(&cursor[d], 1);
  if (pos < CAP)
    entries[d * CAP + pos] = (unsigned int)src[e] | ((unsigned int)r << 16);
}

// ---- bf16 MFMA GEMM: A[M,128] @ B[128, gridDim.y*128] (B given transposed [n][k]).
// N-tiles with n0 <  nsplit  -> Y (bf16, stride nsplit)   [col split is 128-aligned]
// N-tiles with n0 >= nsplit  -> rootOut (f32, stride nroot) + bias; cols >= nroot dropped.
// LDS: XOR-swizzled chunks (16B chunk j stored at j^(row&15)) -> conflict-free frag reads
// Staging: global_load_lds 16B.  Epilogue: swapped-operand MFMA gives each lane 4
// consecutive cols -> pack bf16x4 -> LDS (alias As) -> coalesced 16B global stores.
__global__ __launch_bounds__(256, 2) void k_gemm(
    const unsigned short* __restrict__ A, const unsigned short* __restrict__ BT,
    unsigned short* __restrict__ Y, float* __restrict__ rootOut,
    const float* __restrict__ bias, int M, int nsplit, int nroot) {
  __shared__ __align__(16) unsigned short As[128 * 128];
  __shared__ __align__(16) unsigned short Bs[128 * 128];
  const int tid = threadIdx.x;
  const int m0 = blockIdx.x * 128;
  const int n0 = blockIdx.y * 128;
  const int wv = tid >> 6;
  const int ln = tid & 63;

  // ---- stage 64KB via global_load_lds: wave w covers 64 rows of As (w<2) or Bs ----
  {
    unsigned short* Lbuf = (wv < 2) ? As : Bs;
    const unsigned short* Gbuf = (wv < 2) ? (A + (size_t)m0 * 128) : (BT + (size_t)n0 * 128);
    const int rbase = (wv & 1) * 64;
#pragma unroll
    for (int c = 0; c < 16; ++c) {
      int r = rbase + c * 4 + (ln >> 4);        // row within 128-row buffer
      int c16 = ln & 15;                        // physical 16B chunk
      int j = c16 ^ (r & 15);                   // logical 16B chunk
      const unsigned short* gp = Gbuf + (size_t)r * 128 + j * 8;
      unsigned short* lp = Lbuf + r * 128 + c16 * 8;
      __builtin_amdgcn_global_load_lds((gas_p)(const void*)gp, (las_p)(void*)lp, 16, 0, 0);
    }
  }
  __syncthreads();

  const int lane = tid & 63;
  const int wave = tid >> 6;
  const int wm = (wave >> 1) << 6;
  const int wn = (wave & 1) << 6;
  const int l15 = lane & 15;
  const int quad = lane >> 4;
  f32x4 acc[4][4] = {};
#pragma unroll
  for (int kk = 0; kk < 4; ++kk) {
    const int sw = ((kk * 4 + quad) ^ l15) * 8;   // swizzled byte-chunk offset (shorts)
    bf16x8 af[4], bfr[4];
#pragma unroll
    for (int i = 0; i < 4; ++i) {
      af[i]  = *reinterpret_cast<const bf16x8*>(&As[(wm + i * 16 + l15) * 128 + sw]);
      bfr[i] = *reinterpret_cast<const bf16x8*>(&Bs[(wn + i * 16 + l15) * 128 + sw]);
    }
#pragma unroll
    for (int i = 0; i < 4; ++i)
#pragma unroll
      for (int j = 0; j < 4; ++j)   // swapped operands: lane -> row m, quad*4+r -> col n
        acc[i][j] = __builtin_amdgcn_mfma_f32_16x16x32_bf16(bfr[j], af[i], acc[i][j], 0, 0, 0);
  }

  if (n0 >= nsplit) {
    // ---- root tile: f32 + bias, direct float4 stores ----
#pragma unroll
    for (int i = 0; i < 4; ++i) {
      const int m = wm + i * 16 + l15;
      if (m0 + m >= M) continue;
#pragma unroll
      for (int j = 0; j < 4; ++j) {
        const int col = n0 + wn + j * 16 + quad * 4 - nsplit;
        if (col < nroot) {
          float4 b4 = *reinterpret_cast<const float4*>(&bias[col]);
          float4 v = make_float4(acc[i][j][0] + b4.x, acc[i][j][1] + b4.y,
                                 acc[i][j][2] + b4.z, acc[i][j][3] + b4.w);
          *reinterpret_cast<float4*>(&rootOut[(size_t)(m0 + m) * nroot + col]) = v;
        }
      }
    }
  } else {
    // ---- Y tile: pack bf16x4 -> swizzled LDS (alias As) -> coalesced 16B stores ----
    __syncthreads();                 // all frag reads done; safe to overwrite As
    unsigned short* Cs = As;
#pragma unroll
    for (int i = 0; i < 4; ++i) {
      const int m = wm + i * 16 + l15;
#pragma unroll
      for (int j = 0; j < 4; ++j) {
        const int c8 = ((wn + j * 16) >> 2) + quad;        // logical 8B chunk (0..31)
        const int c8s = c8 ^ (l15 << 1);                   // swizzled
        uint2 pk;
        pk.x = (unsigned int)f2b(acc[i][j][0]) | ((unsigned int)f2b(acc[i][j][1]) << 16);
        pk.y = (unsigned int)f2b(acc[i][j][2]) | ((unsigned int)f2b(acc[i][j][3]) << 16);
        *reinterpret_cast<uint2*>(&Cs[m * 128 + c8s * 4]) = pk;
      }
    }
    __syncthreads();
#pragma unroll
    for (int it = 0; it < 8; ++it) {
      const int L = tid + it * 256;
      const int m = L >> 4;
      const int c16 = L & 15;
      const int c16s = c16 ^ (m & 15);
      if (m0 + m < M) {
        uint4 v = *reinterpret_cast<const uint4*>(&Cs[m * 128 + c16s * 8]);
        *reinterpret_cast<uint4*>(&Y[(size_t)(m0 + m) * nsplit + n0 + c16 * 8]) = v;
      }
    }
  }
}

// ---- layer-1 pull-aggregate: one wave per dst, 2 feats/lane (128 feats).
// Entries bulk-loaded (lane i <- edge i), per-edge 1/cnt via ballots, shfl broadcast.
__global__ void k_agg1(const unsigned int* __restrict__ entries,
                       const int* __restrict__ cursor,
                       const unsigned short* __restrict__ y,
                       const float* __restrict__ hpre,
                       unsigned int* __restrict__ hbf) {
  const int d = blockIdx.x * 4 + (threadIdx.x >> 6);   // NN % 4 == 0
  const int lane = threadIdx.x & 63;
  int deg = cursor[d];
  if (deg > CAP) deg = CAP;
  unsigned int e = (lane < deg) ? entries[d * CAP + lane] : 0u;
  const int myr = (e >> 16) & 7;
  float sc = 0.f;
#pragma unroll
  for (int r = 0; r < 8; ++r) {
    unsigned long long bm = __ballot(lane < deg && myr == r);
    if (myr == r) sc = __builtin_amdgcn_rcpf((float)__popcll(bm));
  }
  if (lane >= deg) sc = 0.f;
  float a0 = 0.f, a1 = 0.f, c0 = 0.f, c1 = 0.f;
  for (int i = 0; i < deg; i += 2) {
    unsigned int e0 = __shfl(e, i, 64);     float s0 = __shfl(sc, i, 64);
    unsigned int e1 = __shfl(e, i + 1, 64); float s1 = __shfl(sc, i + 1, 64);
    unsigned int pk0 = *reinterpret_cast<const unsigned int*>(
        &y[((size_t)(e0 & 0xffffu) << 10) + (((e0 >> 16) & 7u) << 7) + (lane << 1)]);
    unsigned int pk1 = *reinterpret_cast<const unsigned int*>(
        &y[((size_t)(e1 & 0xffffu) << 10) + (((e1 >> 16) & 7u) << 7) + (lane << 1)]);
    a0 += b2f((unsigned short)(pk0 & 0xffffu)) * s0;
    a1 += __uint_as_float(pk0 & 0xffff0000u) * s0;
    c0 += b2f((unsigned short)(pk1 & 0xffffu)) * s1;
    c1 += __uint_as_float(pk1 & 0xffff0000u) * s1;
  }
  a0 += c0; a1 += c1;
  float2 h = reinterpret_cast<const float2*>(hpre)[(size_t)d * 64 + lane];
  a0 = fmaxf(a0 + h.x, 0.f);
  a1 = fmaxf(a1 + h.y, 0.f);
  hbf[(size_t)d * 64 + lane] = (unsigned int)f2b(a0) | ((unsigned int)f2b(a1) << 16);
}

// ---- layer-2 pull-aggregate + classifier: one wave per dst, 64 feats.
// Halves take alternate edges; bulk entries + ballot counts + shfl broadcast.
__global__ void k_agg2(const unsigned int* __restrict__ entries,
                       const int* __restrict__ cursor,
                       const unsigned short* __restrict__ y,
                       const float* __restrict__ hpre,
                       const float* __restrict__ Wc, const float* __restrict__ bc,
                       float* __restrict__ out) {
  const int d = blockIdx.x * 4 + (threadIdx.x >> 6);
  const int lane = threadIdx.x & 63;
  int deg = cursor[d];
  if (deg > CAP) deg = CAP;
  unsigned int e = (lane < deg) ? entries[d * CAP + lane] : 0u;
  const int myr = (e >> 16) & 7;
  float sc = 0.f;
#pragma unroll
  for (int r = 0; r < 8; ++r) {
    unsigned long long bm = __ballot(lane < deg && myr == r);
    if (myr == r) sc = __builtin_amdgcn_rcpf((float)__popcll(bm));
  }
  if (lane >= deg) sc = 0.f;
  const int half = lane >> 5;
  const int l32 = lane & 31;
  float a0 = 0.f, a1 = 0.f;
  const int T = (deg + 1) >> 1;
  for (int t = 0; t < T; ++t) {
    int i = 2 * t + half;                    // i<=63; i>=deg edges have sc=0
    unsigned int ei = __shfl(e, i, 64);
    float si = __shfl(sc, i, 64);
    unsigned int pk = *reinterpret_cast<const unsigned int*>(
        &y[((size_t)(ei & 0xffffu) << 9) + (((ei >> 16) & 7u) << 6) + (l32 << 1)]);
    a0 += b2f((unsigned short)(pk & 0xffffu)) * si;
    a1 += __uint_as_float(pk & 0xffff0000u) * si;
  }
  a0 += __shfl_xor(a0, 32, 64);
  a1 += __shfl_xor(a1, 32, 64);
  float2 h = reinterpret_cast<const float2*>(hpre)[(size_t)d * 32 + l32];
  float v0 = fmaxf(a0 + h.x, 0.f);
  float v1 = fmaxf(a1 + h.y, 0.f);
  int f0 = l32 << 1;
  float p0 = v0 * Wc[f0 * 2 + 0] + v1 * Wc[f0 * 2 + 2];
  float p1 = v0 * Wc[f0 * 2 + 1] + v1 * Wc[f0 * 2 + 3];
#pragma unroll
  for (int off = 16; off > 0; off >>= 1) {
    p0 += __shfl_down(p0, off, 64);
    p1 += __shfl_down(p1, off, 64);
  }
  if (lane == 0) {
    out[d * 2 + 0] = p0 + bc[0];
    out[d * 2 + 1] = p1 + bc[1];
  }
}

extern "C" void kernel_launch(void* const* d_in, const int* in_sizes, int n_in,
                              void* d_out, int out_size, void* d_ws, size_t ws_size,
                              hipStream_t stream) {
  const float* x     = (const float*)d_in[0];
  const int*   ei    = (const int*)d_in[1];
  const int*   et    = (const int*)d_in[2];
  const float* W1    = (const float*)d_in[3];
  const float* root1 = (const float*)d_in[4];
  const float* b1    = (const float*)d_in[5];
  const float* W2    = (const float*)d_in[6];
  const float* root2 = (const float*)d_in[7];
  const float* b2    = (const float*)d_in[8];
  const float* Wc    = (const float*)d_in[9];
  const float* bc    = (const float*)d_in[10];
  const int* srcI = ei;        // edge_index[0]
  const int* dstI = ei + EE;   // edge_index[1]

  char* ws = (char*)d_ws;
  unsigned short* xb      = (unsigned short*)(ws);             // 12,800,000 B
  unsigned int*   hbf     = (unsigned int*)(ws);               // alias (xb dead after gemm1)
  unsigned short* B1T     = (unsigned short*)(ws + 12800000);  //    294,912 B
  unsigned short* B2T     = (unsigned short*)(ws + 13094912);  //    163,840 B
  int*            cursor  = (int*)(ws + 13258752);             //    200,000 B
  unsigned int*   entries = (unsigned int*)(ws + 13458752);    // 12,800,000 B (50000*64*4)
  float*          hpre    = (float*)(ws + 26258752);           // 25,600,000 B (reused layer 2)
  unsigned short* y1      = (unsigned short*)(ws + 51858752);  // 102,400,000 B
  unsigned short* y2      = y1;                                // alias (y1 dead after agg1)
  // total: 154,258,752 B

  hipMemsetAsync(cursor, 0, 200000, stream);
  k_f32_to_bf16_x4<<<(1600000 + 255) / 256, 256, 0, stream>>>(x, xb, 1600000);
  k_build_b1<<<(1152 * 128 + 255) / 256, 256, 0, stream>>>(W1, root1, B1T);
  k_build_b2<<<(640 * 128 + 255) / 256, 256, 0, stream>>>(W2, root2, B2T);
  k_edges<<<(EE + 255) / 256, 256, 0, stream>>>(srcI, dstI, et, cursor, entries);

  // layer 1: y1 = xb @ [W1_0..W1_7] (bf16), hpre = xb @ root1 + b1 (f32)
  k_gemm<<<dim3(391, 9), 256, 0, stream>>>(xb, B1T, y1, hpre, b1, NN, 1024, 128);
  k_agg1<<<NN / 4, 256, 0, stream>>>(entries, cursor, y1, hpre, hbf);

  // layer 2: y2 = hbf @ [W2_0..W2_7] (bf16), hpre = hbf @ root2 + b2 (f32)
  k_gemm<<<dim3(391, 5), 256, 0, stream>>>((const unsigned short*)hbf, B2T, y2, hpre, b2, NN, 512, 64);
  k_agg2<<<NN / 4, 256, 0, stream>>>(entries, cursor, y2, hpre, Wc, bc, (float*)d_out);
}